// Round 1
// baseline (518.971 us; speedup 1.0000x reference)
//
#include <hip/hip_runtime.h>

#define BB 4
#define CC 256
#define HH 96
#define WW 128
#define PP 9
#define OFF 4
#define CCH 16           // channels per chunk
#define NPAIR (CCH / 2)  // 8 f16x2 channel pairs per chunk
#define NCH (CC / CCH)   // 16 chunks
#define TPB 288          // 9 dy * 32 pixel-groups
#define TW 72            // staged in2 cols (64 out + 8 halo)
#define XCOLS 64         // output columns per block

typedef _Float16 h2 __attribute__((ext_vector_type(2)));

__device__ __forceinline__ h2 u2h(unsigned u) { union { unsigned u; h2 h; } x; x.u = u; return x.h; }

#if __has_builtin(__builtin_amdgcn_fdot2)
__device__ __forceinline__ float dot2(h2 a, h2 b, float c) { return __builtin_amdgcn_fdot2(a, b, c, false); }
#else
__device__ __forceinline__ float dot2(h2 a, h2 b, float c) { return c + (float)a[0] * (float)b[0] + (float)a[1] * (float)b[1]; }
#endif

__device__ __forceinline__ unsigned pk(float a, float b) {
#if __has_builtin(__builtin_amdgcn_cvt_pkrtz)
  auto r = __builtin_amdgcn_cvt_pkrtz(a, b);
  unsigned u; __builtin_memcpy(&u, &r, 4); return u;
#else
  h2 h; h[0] = (_Float16)a; h[1] = (_Float16)b;
  unsigned u; __builtin_memcpy(&u, &h, 4); return u;
#endif
}

// Barrier WITHOUT the __syncthreads vmcnt(0) drain: waits only LDS ops, so
// prefetch global loads stay in flight across the barrier (T4 / AITER style).
// The "memory" clobbers pin issued loads above the barrier (no sinking) and
// keep next-phase ds_reads below it (no hoisting).
__device__ __forceinline__ void bar_lgkm() {
  __builtin_amdgcn_sched_barrier(0);
  asm volatile("s_waitcnt lgkmcnt(0)" ::: "memory");
  __builtin_amdgcn_s_barrier();
  asm volatile("" ::: "memory");
  __builtin_amdgcn_sched_barrier(0);
}

// 768 blocks = 4b * 96h * 2xh = exactly 3 blocks/CU.
// Double-buffered LDS (45.5 KB): one barrier per chunk, prefetch for chunk
// c+2 issued before the barrier and consumed one full compute phase later.
__global__ __launch_bounds__(TPB, 4) void corr_kernel(const float* __restrict__ in1,
                                                      const float* __restrict__ in2,
                                                      float* __restrict__ out) {
  __shared__ unsigned s2[2][NPAIR][PP][TW];   // 2 x 20736 B
  __shared__ unsigned s1[2][NPAIR][XCOLS];    // 2 x 2048 B -> 45.5 KB total

  // XCD swizzle: 12-row h-band per XCD so the 9-row dy-halo stays in-XCD L2.
  const int bx = blockIdx.x;
  const int xcd = bx & 7;
  const int slot = bx >> 3;            // 0..95
  const int xh = slot & 1;
  const int s3 = slot >> 1;            // 0..47
  const int b = s3 / 12;
  const int h = xcd * 12 + (s3 % 12);
  const int xbase = xh * XCOLS;

  const int tid = threadIdx.x;
  const int dy = tid >> 5;             // 0..8
  const int pxg = tid & 31;            // 0..31
  const int L0 = pxg << 1;             // 2 output px -> lds cols L0, L0+1

  // staging role: 288 = 8 pairs * 36 col-pairs; col pairs are edge-aligned
  // (OOB pairs are fully OOB), so validity is a single per-lane bool.
  const int sp = tid / 36;             // channel pair 0..7
  const int sc2 = tid - sp * 36;       // col-pair 0..35
  const int sL = sc2 << 1;
  const int sgx = xbase - OFF + sL;    // global x of staged pair (even)
  const bool colv = (sgx >= 0) && (sgx < WW);
  // row validity is block-uniform (scalar branches only)
  const int rlo = (h >= OFF) ? 0 : (OFF - h);
  const int rhi = (PP < HH + OFF - h) ? PP : (HH + OFF - h);

  const int plane = HH * WW;           // 12288
  const long base_b = (long)b * CC * plane;

  // hoisted base pointers (advance by CCH*plane per chunk)
  const float* p2a = in2 + base_b + (long)(2 * sp) * plane + (long)(h - OFF) * WW + sgx;
  const float* p2b = p2a + plane;
  const int i1p = tid >> 5, i1c = tid & 31;  // in1 role (tid<256)
  const float* p1a = in1 + base_b + (long)(2 * i1p) * plane + h * WW + xbase + (i1c << 1);
  const float* p1b = p1a + plane;

  // pre-zero BOTH s2 buffers once: OOB rows/cols never written afterwards
  for (int i = tid; i < 2 * NPAIR * PP * TW; i += TPB) ((unsigned*)s2)[i] = 0u;

  float acc[2][PP];
#pragma unroll
  for (int px = 0; px < 2; ++px)
#pragma unroll
    for (int dx = 0; dx < PP; ++dx) acc[px][dx] = 0.f;

  // prefetch registers (held live across barriers — ~40 VGPRs, intended)
  float2 fa[PP], fb[PP], ga, gb;

  auto PREFETCH = [&](int c) {
    const long adv = (long)c * CCH * plane;
    if (colv) {
#pragma unroll
      for (int r = 0; r < PP; ++r)
        if (r >= rlo && r < rhi) {
          fa[r] = *(const float2*)(p2a + adv + r * WW);
          fb[r] = *(const float2*)(p2b + adv + r * WW);
        }
    }
    if (tid < NPAIR * 32) {
      ga = *(const float2*)(p1a + adv);
      gb = *(const float2*)(p1b + adv);
    }
  };

  auto STORE = [&](int buf) {
    if (colv) {
#pragma unroll
      for (int r = 0; r < PP; ++r)
        if (r >= rlo && r < rhi)
          *(uint2*)&s2[buf][sp][r][sL] = make_uint2(pk(fa[r].x, fb[r].x), pk(fa[r].y, fb[r].y));
    }
    if (tid < NPAIR * 32)
      *(uint2*)&s1[buf][i1p][i1c << 1] = make_uint2(pk(ga.x, gb.x), pk(ga.y, gb.y));
  };

  // ---- prologue: prefetch chunk 0, make pre-zero visible
  PREFETCH(0);
  bar_lgkm();          // covers the pre-zero; chunk-0 loads stay in flight

  STORE(0);            // consumes chunk-0 regs (backend inserts precise vmcnt)
  PREFETCH(1);         // in flight across the barrier
  bar_lgkm();          // buf0 visible

#pragma unroll 1
  for (int c = 0; c < NCH; ++c) {
    const unsigned (*S2)[PP][TW] = s2[c & 1];
    const unsigned (*S1)[XCOLS] = s1[c & 1];

    // ---- compute chunk c: 2px x 9dx sliding f16x2 window
#pragma unroll
    for (int p = 0; p < NPAIR; ++p) {
      unsigned q[2], w[10];
      *(uint2*)q = *(const uint2*)&S1[p][L0];
#pragma unroll
      for (int i = 0; i < 5; ++i)
        *(uint2*)&w[2 * i] = *(const uint2*)&S2[p][dy][L0 + 2 * i];
#pragma unroll
      for (int px = 0; px < 2; ++px)
#pragma unroll
        for (int dx = 0; dx < PP; ++dx)
          acc[px][dx] = dot2(u2h(w[px + dx]), u2h(q[px]), acc[px][dx]);
    }

    if (c + 1 < NCH) {
      STORE((c + 1) & 1);          // other buffer: safe vs concurrent readers
      if (c + 2 < NCH) PREFETCH(c + 2);
      bar_lgkm();                  // writes visible; loads remain in flight
    }
  }

  // ---- epilogue: 9 coalesced float2 stores
  const int gx0 = xbase + L0;
  float* ob = out + ((long)(b * PP + dy) * PP) * plane + h * WW + gx0;
#pragma unroll
  for (int dx = 0; dx < PP; ++dx)
    *(float2*)(ob + (long)dx * plane) = make_float2(acc[0][dx], acc[1][dx]);
}

extern "C" void kernel_launch(void* const* d_in, const int* in_sizes, int n_in,
                              void* d_out, int out_size, void* d_ws, size_t ws_size,
                              hipStream_t stream) {
  const float* in1 = (const float*)d_in[0];
  const float* in2 = (const float*)d_in[1];
  float* out = (float*)d_out;
  // 768 blocks = 4b * 96h * 2xh (xcd-swizzled), 288 thr = 9dy * 32pxg
  corr_kernel<<<dim3(BB * HH * 2), dim3(TPB), 0, stream>>>(in1, in2, out);
}

// Round 2
// 259.339 us; speedup vs baseline: 2.0011x; 2.0011x over previous
//
#include <hip/hip_runtime.h>

#define BB 4
#define CC 256
#define HH 96
#define WW 128
#define PP 9
#define OFF 4
#define CCH 16           // channels per chunk
#define NPAIR (CCH / 2)  // 8 f16x2 channel pairs per chunk
#define NCH (CC / CCH)   // 16 chunks
#define TPB 288          // 9 dy * 32 pixel-groups
#define TW 72            // staged in2 cols (64 out + 8 halo)
#define XCOLS 64         // output columns per block

typedef _Float16 h2 __attribute__((ext_vector_type(2)));

__device__ __forceinline__ h2 u2h(unsigned u) { union { unsigned u; h2 h; } x; x.u = u; return x.h; }

#if __has_builtin(__builtin_amdgcn_fdot2)
__device__ __forceinline__ float dot2(h2 a, h2 b, float c) { return __builtin_amdgcn_fdot2(a, b, c, false); }
#else
__device__ __forceinline__ float dot2(h2 a, h2 b, float c) { return c + (float)a[0] * (float)b[0] + (float)a[1] * (float)b[1]; }
#endif

__device__ __forceinline__ unsigned pk(float a, float b) {
#if __has_builtin(__builtin_amdgcn_cvt_pkrtz)
  auto r = __builtin_amdgcn_cvt_pkrtz(a, b);
  unsigned u; __builtin_memcpy(&u, &r, 4); return u;
#else
  h2 h; h[0] = (_Float16)a; h[1] = (_Float16)b;
  unsigned u; __builtin_memcpy(&u, &h, 4); return u;
#endif
}

// 768 blocks = 4b * 96h * 2xh = 3 blocks/CU (LDS-capped at 3 anyway).
// Pipeline: PREFETCH(c+1) issued at phase start, consumed by STORE(c+1) at
// phase end -> loads overlap the whole compute phase, and NOTHING is live
// across a barrier (so __syncthreads' vmcnt(0) drain is free).
// launch_bounds(.,3): VGPR cap >=128 for the ~110-reg working set (the
// round-1 spill was the 40-reg prefetch state vs a 64-reg budget).
__global__ __launch_bounds__(TPB, 3) void corr_kernel(const float* __restrict__ in1,
                                                      const float* __restrict__ in2,
                                                      float* __restrict__ out) {
  __shared__ unsigned s2[2][NPAIR][PP][TW];   // 2 x 20736 B
  __shared__ unsigned s1[2][NPAIR][XCOLS];    // 2 x 2048 B -> 45.5 KB total

  // XCD swizzle: 12-row h-band per XCD so the 9-row dy-halo stays in-XCD L2.
  const int bx = blockIdx.x;
  const int xcd = bx & 7;
  const int slot = bx >> 3;            // 0..95
  const int xh = slot & 1;
  const int s3 = slot >> 1;            // 0..47
  const int b = s3 / 12;
  const int h = xcd * 12 + (s3 % 12);
  const int xbase = xh * XCOLS;

  const int tid = threadIdx.x;
  const int dy = tid >> 5;             // 0..8
  const int pxg = tid & 31;            // 0..31
  const int L0 = pxg << 1;             // 2 output px -> lds cols L0, L0+1

  // staging role: 288 = 8 pairs * 36 col-pairs; col pairs are edge-aligned.
  const int sp = tid / 36;             // channel pair 0..7
  const int sc2 = tid - sp * 36;       // col-pair 0..35
  const int sL = sc2 << 1;
  const int sgx = xbase - OFF + sL;    // global x of staged pair (even)
  const bool colv = (sgx >= 0) && (sgx < WW);
  const int sgxc = sgx < 0 ? 0 : (sgx > WW - 2 ? WW - 2 : sgx);  // clamped (branchless loads)
  // row validity is block-uniform
  const int rlo = (h >= OFF) ? 0 : (OFF - h);
  const int rhi = (PP < HH + OFF - h) ? PP : (HH + OFF - h);

  const int plane = HH * WW;           // 12288
  const long base_b = (long)b * CC * plane;

  // hoisted base pointers (advance by CCH*plane per chunk)
  const float* p2a = in2 + base_b + (long)(2 * sp) * plane + (long)(h - OFF) * WW + sgxc;
  const float* p2b = p2a + plane;
  const int i1p = tid >> 5, i1c = tid & 31;            // in1 role (tid<256)
  const int i1pc = (i1p < NPAIR) ? i1p : (NPAIR - 1);  // clamp: branchless load, guarded store
  const float* p1a = in1 + base_b + (long)(2 * i1pc) * plane + h * WW + xbase + (i1c << 1);
  const float* p1b = p1a + plane;

  // clamped row byte-offsets: loads always in-bounds; OOB rows simply never stored
  int roff[PP];
#pragma unroll
  for (int r = 0; r < PP; ++r) {
    const int rc = (r < rlo) ? rlo : ((r >= rhi) ? (rhi - 1) : r);
    roff[r] = rc * WW;
  }

  // pre-zero BOTH s2 buffers once: OOB rows/cols never written afterwards
  for (int i = tid; i < 2 * NPAIR * PP * TW; i += TPB) ((unsigned*)s2)[i] = 0u;

  float acc[2][PP];
#pragma unroll
  for (int px = 0; px < 2; ++px)
#pragma unroll
    for (int dx = 0; dx < PP; ++dx) acc[px][dx] = 0.f;

  // prefetch registers: live from PREFETCH (phase start) to STORE (phase end),
  // never across a barrier.
  float2 fa[PP], fb[PP], ga, gb;

  auto PREFETCH = [&](int c) {
    const long adv = (long)c * CCH * plane;
#pragma unroll
    for (int r = 0; r < PP; ++r) {
      fa[r] = *(const float2*)(p2a + adv + roff[r]);
      fb[r] = *(const float2*)(p2b + adv + roff[r]);
    }
    ga = *(const float2*)(p1a + adv);
    gb = *(const float2*)(p1b + adv);
  };

  auto STORE = [&](int buf) {
    if (colv) {
#pragma unroll
      for (int r = 0; r < PP; ++r)
        if (r >= rlo && r < rhi)
          *(uint2*)&s2[buf][sp][r][sL] = make_uint2(pk(fa[r].x, fb[r].x), pk(fa[r].y, fb[r].y));
    }
    if (tid < NPAIR * 32)
      *(uint2*)&s1[buf][i1p][i1c << 1] = make_uint2(pk(ga.x, gb.x), pk(ga.y, gb.y));
  };

  auto COMPUTE = [&](int buf) {
    const unsigned (*S2)[PP][TW] = s2[buf];
    const unsigned (*S1)[XCOLS] = s1[buf];
#pragma unroll
    for (int p = 0; p < NPAIR; ++p) {
      unsigned q[2], w[10];
      *(uint2*)q = *(const uint2*)&S1[p][L0];
#pragma unroll
      for (int i = 0; i < 5; ++i)
        *(uint2*)&w[2 * i] = *(const uint2*)&S2[p][dy][L0 + 2 * i];
#pragma unroll
      for (int px = 0; px < 2; ++px)
#pragma unroll
        for (int dx = 0; dx < PP; ++dx)
          acc[px][dx] = dot2(u2h(w[px + dx]), u2h(q[px]), acc[px][dx]);
    }
  };

  // ---- prologue
  PREFETCH(0);
  __builtin_amdgcn_sched_barrier(0);   // pin chunk-0 load issue above the barrier
  __syncthreads();                     // pre-zero visible (one-time vmcnt drain, prologue only)
  STORE(0);
  __syncthreads();                     // buf0 visible

  // ---- main loop: no branches, one barrier per chunk
#pragma unroll 1
  for (int c = 0; c < NCH - 1; ++c) {
    PREFETCH(c + 1);                   // issue: in flight during compute
    __builtin_amdgcn_sched_barrier(0); // forbid sinking the loads into STORE
    COMPUTE(c & 1);                    // ~800 cy of dot2 covers the L2 latency
    STORE((c + 1) & 1);                // consume: other buffer, pre-barrier
    __syncthreads();                   // vmcnt already drained by STORE -> cheap
  }
  COMPUTE((NCH - 1) & 1);              // peeled last chunk: no store, no barrier

  // ---- epilogue: 9 coalesced float2 stores
  const int gx0 = xbase + L0;
  float* ob = out + ((long)(b * PP + dy) * PP) * plane + h * WW + gx0;
#pragma unroll
  for (int dx = 0; dx < PP; ++dx)
    *(float2*)(ob + (long)dx * plane) = make_float2(acc[0][dx], acc[1][dx]);
}

extern "C" void kernel_launch(void* const* d_in, const int* in_sizes, int n_in,
                              void* d_out, int out_size, void* d_ws, size_t ws_size,
                              hipStream_t stream) {
  const float* in1 = (const float*)d_in[0];
  const float* in2 = (const float*)d_in[1];
  float* out = (float*)d_out;
  // 768 blocks = 4b * 96h * 2xh (xcd-swizzled), 288 thr = 9dy * 32pxg
  corr_kernel<<<dim3(BB * HH * 2), dim3(TPB), 0, stream>>>(in1, in2, out);
}

// Round 3
// 145.495 us; speedup vs baseline: 3.5669x; 1.7825x over previous
//
#include <hip/hip_runtime.h>

#define BB 4
#define CC 256
#define HH 96
#define WW 128
#define PP 9
#define OFF 4
#define PLANE (HH * WW)      // 12288

#define HB 3                 // output rows per WG
#define RN (HB + 8)          // 11 staged in2 rows
#define PX 32                // output px per WG
#define SW 48                // staged in2 cols (32 + 16 halo, aligned tiles)
#define PAD 20               // u32 stride per px: 16 c-pairs + 4 pad (stride/4 odd -> 16B-granule full-rank, no bank conflict)
#define KCH 32               // channels per chunk = MFMA K
#define NCHK (CC / KCH)      // 8
#define TPB 384              // 6 waves = 3 rows x 2 px-blocks
#define DPAD 36              // f32 px1-stride in D scratch (mult of 4 for b128, 9*stride/4 co-prime banks)

typedef _Float16 f16x8 __attribute__((ext_vector_type(8)));
typedef float fx4 __attribute__((ext_vector_type(4)));

union U16 { uint4 u; f16x8 h; };

__device__ __forceinline__ unsigned pk(float a, float b) {
#if __has_builtin(__builtin_amdgcn_cvt_pkrtz)
  auto r = __builtin_amdgcn_cvt_pkrtz(a, b);
  unsigned u; __builtin_memcpy(&u, &r, 4); return u;
#else
  _Float16 h0 = (_Float16)a, h1 = (_Float16)b;
  unsigned u = 0; __builtin_memcpy(&u, &h0, 2); unsigned v = 0; __builtin_memcpy(&v, &h1, 2);
  return u | (v << 16);
#endif
}

// MFMA formulation: D[px1,px2] = sum_c in1[c,px1]*in2[c,px2]; out(dy,dx,px1) = D_dy[px1, px1+dx-4].
// WG = (b, 3-row band, 32 px): 512 WGs = exactly 2/CU. 6 waves; wave (wr,wp) owns
// px1-block [16wp,16wp+16) of row wr, all 9 dy, 2 aligned px2-tiles -> 18 f32x4 accums.
// LDS layout [row][px][c-pair] with pad 20: B-frag (8 consecutive c for fixed px2) = one b128.
__global__ __launch_bounds__(TPB, 3) void corr_kernel(const float* __restrict__ in1,
                                                      const float* __restrict__ in2,
                                                      float* __restrict__ out) {
  __shared__ __align__(16) unsigned s2[RN][SW][PAD];  // 42240 B
  __shared__ __align__(16) unsigned s1[HB][PX][PAD];  //  7680 B  -> 49.9 KB

  // XCD swizzle: XCD k owns h-bands 4k..4k+3 (12 rows) for all b -> per-chunk
  // in2 slice 4b*32c*20r*128px*4B ~ 1.3 MB fits the 4 MB XCD L2.
  const int bx = blockIdx.x;
  const int xcd = bx & 7;
  const int s = bx >> 3;           // 0..63
  const int xq = s & 3;
  const int t2 = s >> 2;           // 0..15
  const int b = t2 & 3;
  const int band = xcd * 4 + (t2 >> 2);
  const int h0 = band * HB;

  const int tid = threadIdx.x;
  // compute role: wave (wr, wp), lane (ln, lg)
  const int wv = tid >> 6;
  const int wr = wv >> 1;          // row 0..2
  const int wp = wv & 1;           // px1-block 0..1
  const int lane = tid & 63;
  const int ln = lane & 15;        // MFMA m/n index
  const int lg = lane >> 4;        // MFMA k-group

  // in2 staging role: (c-block, row-phase) x 48 px
  const int spx = tid % 48;
  const int sq = tid / 48;         // 0..7
  const int scb = sq & 3;          // c-block (8 channels)
  const int sr0 = sq >> 2;         // 0..1
  const int gx2 = xq * PX - OFF + spx;
  const bool okx = (unsigned)gx2 < WW;
  // in1 staging role: exactly 1 slot/thread
  const int tpx = tid & 31;
  const int tq = tid >> 5;         // 0..11
  const int tcb = tq & 3;
  const int tr = tq >> 2;          // 0..2

  const long cpl = (long)PLANE;
  const float* b2 = in2 + ((long)b * CC + scb * 8) * cpl + gx2;
  const float* b1 = in1 + ((long)b * CC + tcb * 8) * cpl + (long)(h0 + tr) * WW + xq * PX + tpx;

  // pre-zero s2: OOB halo slots stay zero (never rewritten)
  for (int i = tid; i < RN * SW * PAD; i += TPB) ((unsigned*)s2)[i] = 0u;
  __syncthreads();  // pre-zero visible before staging overwrites valid slots

  fx4 acc[PP][2];
#pragma unroll
  for (int dy = 0; dy < PP; ++dy)
#pragma unroll
    for (int t = 0; t < 2; ++t) acc[dy][t] = (fx4)0.f;

#pragma unroll 1
  for (int c = 0; c < NCHK; ++c) {
    const long cadv = (long)c * KCH * cpl;
    // ---- stage in2: 8 channels (4 c-pairs) per slot -> one b128 LDS write
#pragma unroll
    for (int k = 0; k < 6; ++k) {
      const int r = sr0 + 2 * k;
      const int rg = h0 - OFF + r;
      if (r < RN && okx && (unsigned)rg < HH) {
        const float* p = b2 + cadv + (long)rg * WW;
        const float l0 = p[0], l1 = p[cpl], l2 = p[2 * cpl], l3 = p[3 * cpl];
        const float l4 = p[4 * cpl], l5 = p[5 * cpl], l6 = p[6 * cpl], l7 = p[7 * cpl];
        uint4 w;
        w.x = pk(l0, l1); w.y = pk(l2, l3); w.z = pk(l4, l5); w.w = pk(l6, l7);
        *(uint4*)&s2[r][spx][4 * scb] = w;
      }
    }
    // ---- stage in1 (always in-bounds)
    {
      const float* p = b1 + cadv;
      const float l0 = p[0], l1 = p[cpl], l2 = p[2 * cpl], l3 = p[3 * cpl];
      const float l4 = p[4 * cpl], l5 = p[5 * cpl], l6 = p[6 * cpl], l7 = p[7 * cpl];
      uint4 w;
      w.x = pk(l0, l1); w.y = pk(l2, l3); w.z = pk(l4, l5); w.w = pk(l6, l7);
      *(uint4*)&s1[tr][tpx][4 * tcb] = w;
    }
    __syncthreads();

    // ---- compute: A (in1) reused across all 18 MFMAs of this chunk
    U16 a; a.u = *(const uint4*)&s1[wr][wp * 16 + ln][4 * lg];
#pragma unroll
    for (int dy = 0; dy < PP; ++dy) {
#pragma unroll
      for (int t = 0; t < 2; ++t) {
        U16 bb; bb.u = *(const uint4*)&s2[wr + dy][wp * 16 + 16 * t + ln][4 * lg];
        acc[dy][t] = __builtin_amdgcn_mfma_f32_16x16x32_f16(a.h, bb.h, acc[dy][t], 0, 0, 0);
      }
    }
    __syncthreads();
  }

  // ---- epilogue: per dy, dump D tiles to LDS scratch, read diagonals, store.
  // D layout (verified m89/m91): col(n=px2) = lane&15, row(m=px1) = (lane>>4)*4 + reg.
  float* DL = (float*)&s2[0][0][0];  // [HB][SW][DPAD] f32 = 20.25 KB overlay
#pragma unroll
  for (int dy = 0; dy < PP; ++dy) {
#pragma unroll
    for (int t = 0; t < 2; ++t) {
      const int p2 = wp * 16 + 16 * t + ln;
      *(fx4*)&DL[(wr * SW + p2) * DPAD + wp * 16 + 4 * lg] = acc[dy][t];
    }
    __syncthreads();
#pragma unroll
    for (int k = 0; k < 3; ++k) {
      const int id = tid + TPB * k;
      if (id < HB * PP * PX) {
        const int px = id & 31;
        const int v = id >> 5;       // 0..26
        const int dx = v % PP;
        const int rr = v / PP;
        const float val = DL[(rr * SW + px + dx) * DPAD + px];  // px2w = px1 + dx - 4 + 4halo
        out[(long)((b * PP + dy) * PP + dx) * PLANE + (long)(h0 + rr) * WW + xq * PX + px] = val;
      }
    }
    __syncthreads();
  }
}

extern "C" void kernel_launch(void* const* d_in, const int* in_sizes, int n_in,
                              void* d_out, int out_size, void* d_ws, size_t ws_size,
                              hipStream_t stream) {
  const float* in1 = (const float*)d_in[0];
  const float* in2 = (const float*)d_in[1];
  float* out = (float*)d_out;
  // 512 blocks = 4b * 32 bands * 4 xq (xcd-swizzled) = exactly 2 WG/CU
  corr_kernel<<<dim3(512), dim3(TPB), 0, stream>>>(in1, in2, out);
}